// Round 8
// baseline (88.722 us; speedup 1.0000x reference)
//
#include <hip/hip_runtime.h>
#include <math.h>

// Fixed shapes: b_edges (64,1,512,512) f32, sobel (64,2,512,512) f32
// BASE=256, PY_SIZES=[256,64]
// Group g = b*64 + R owns output rows 4R..4R+3 (input rows 8R..8R+7).
// prepE: one wave per group; lane X owns cols 4X..4X+3 == one level-1 cell.
// prepSa: one wave per (group, y-half); block (4 waves = 2 groups) stages its
//   contiguous span of output rows in LDS, then writes all 8 sections as
//   dense float4 streams (address-throughput, not bytes, is the VMEM limit).
// 512->256 align-corners: pos(i)=i*511/255 (exact f32 product, IEEE div),
// lo(i)=2i, w=pos-2i (i=255 -> w=1.0, bit-identical to the lo=hi=511 form).

typedef unsigned long long u64;
#define OFFSET1 4194304   // lin_id offset of level 1 (=64*256*256)

// ---------------------------------------------------------------------------
// prepE: E-only pass. 16 upfront float4 loads per lane (rows 8R..8R+7, cols
// 8X..8X+7), predicates for the lane's 16 pixels, ballots -> counts + masks.
// ---------------------------------------------------------------------------
__global__ __launch_bounds__(256) void prepE_kernel(const float* __restrict__ E,
                                                    unsigned short* __restrict__ pred16,
                                                    u64* __restrict__ mask1,
                                                    int* __restrict__ counts0,
                                                    int* __restrict__ counts1) {
    int lane = threadIdx.x & 63;
    int g = blockIdx.x * 4 + (threadIdx.x >> 6);     // 0..4095
    int b = g >> 6, R = g & 63;

    const float* Ep = E + b * 262144 + (8 * R) * 512 + 8 * lane;
    float4 L[8], H[8];
    #pragma unroll
    for (int k = 0; k < 8; ++k) {
        L[k] = *(const float4*)(Ep + k * 512);
        H[k] = *(const float4*)(Ep + k * 512 + 4);
    }

    float wx[4], cwx[4];
    #pragma unroll
    for (int j = 0; j < 4; ++j) {
        int xi = 4 * lane + j;
        wx[j] = (float)(xi * 511) / 255.0f - (float)(8 * lane + 2 * j);
        cwx[j] = 1.0f - wx[j];
    }

    unsigned pred = 0;
    int rc = 0;
    #pragma unroll
    for (int r = 0; r < 4; ++r) {
        int y = 4 * R + r;
        float wy = (float)(y * 511) / 255.0f - (float)(2 * y);
        float cwy = 1.0f - wy;
        float4 lo = L[2 * r], loh = H[2 * r];
        float4 hi = L[2 * r + 1], hih = H[2 * r + 1];
        float e0 = (lo.x*cwy + hi.x*wy)*cwx[0] + (lo.y*cwy + hi.y*wy)*wx[0];
        float e1 = (lo.z*cwy + hi.z*wy)*cwx[1] + (lo.w*cwy + hi.w*wy)*wx[1];
        float e2 = (loh.x*cwy + hih.x*wy)*cwx[2] + (loh.y*cwy + hih.y*wy)*wx[2];
        float e3 = (loh.z*cwy + hih.z*wy)*cwx[3] + (loh.w*cwy + hih.w*wy)*wx[3];
        bool p0 = (e0 != 0.0f), p1 = (e1 != 0.0f), p2 = (e2 != 0.0f), p3 = (e3 != 0.0f);
        pred |= (p0?1u:0u) << (4*r+0);
        pred |= (p1?1u:0u) << (4*r+1);
        pred |= (p2?1u:0u) << (4*r+2);
        pred |= (p3?1u:0u) << (4*r+3);
        u64 b0 = __ballot(p0), b1 = __ballot(p1), b2 = __ballot(p2), b3 = __ballot(p3);
        rc += __popcll(b0) + __popcll(b1) + __popcll(b2) + __popcll(b3);
    }
    u64 m1 = __ballot(pred != 0);
    pred16[g * 64 + lane] = (unsigned short)pred;
    if (lane == 0) {
        counts0[g] = rc;
        counts1[g] = __popcll(m1);
        mask1[g] = m1;
    }
}

// single-block exclusive scan of counts0[4096] and counts1[4096] (+sentinels)
__global__ __launch_bounds__(1024) void scan_kernel(const int* __restrict__ counts0,
                                                    int* __restrict__ offs0,
                                                    const int* __restrict__ counts1,
                                                    int* __restrict__ offs1,
                                                    int* __restrict__ totals) {
    __shared__ int wsum[16];
    int tid = threadIdx.x, lane = tid & 63, wave = tid >> 6;

    int carry = 0;
    for (int base = 0; base < 4096; base += 1024) {
        int v = counts0[base + tid];
        int inc = v;
        #pragma unroll
        for (int d = 1; d < 64; d <<= 1) {
            int t = __shfl_up(inc, (unsigned)d, 64);
            if (lane >= d) inc += t;
        }
        if (lane == 63) wsum[wave] = inc;
        __syncthreads();
        int wbase = 0;
        for (int i = 0; i < wave; ++i) wbase += wsum[i];
        int tot = 0;
        #pragma unroll
        for (int i = 0; i < 16; ++i) tot += wsum[i];
        offs0[base + tid] = carry + wbase + inc - v;
        carry += tot;
        __syncthreads();
    }
    if (tid == 0) { totals[0] = carry; offs0[4096] = carry; }

    int carry1 = 0;
    for (int base = 0; base < 4096; base += 1024) {
        int v = counts1[base + tid];
        int inc = v;
        #pragma unroll
        for (int d = 1; d < 64; d <<= 1) {
            int t = __shfl_up(inc, (unsigned)d, 64);
            if (lane >= d) inc += t;
        }
        if (lane == 63) wsum[wave] = inc;
        __syncthreads();
        int wbase = 0;
        for (int i = 0; i < wave; ++i) wbase += wsum[i];
        int tot = 0;
        #pragma unroll
        for (int i = 0; i < 16; ++i) tot += wsum[i];
        offs1[base + tid] = carry1 + wbase + inc - v;
        carry1 += tot;
        __syncthreads();
    }
    if (tid == 0) { totals[1] = carry1; offs1[4096] = carry1; }
}

// ---------------------------------------------------------------------------
// staged writeout: per-row payload (v0,v1,pid,prw) in LDS; emit all 8 output
// sections as dense float4 streams with scalar head/tail for 16B alignment.
// Derived values recomputed with the SAME fp expression order as before.
// level 0: pid = (b<<16)|(y<<8)|x ; level 1: pid = b*4096 + R*64 + X.
// ---------------------------------------------------------------------------
__device__ __forceinline__ float stage_val(int kind, int width, int f,
                                           const float* lv0, const float* lv1,
                                           const int* lpid, const int* lprw,
                                           int level) {
    int row = (width == 2) ? (f >> 1) : f;
    int c   = (width == 2) ? (f & 1) : 0;
    float v0 = lv0[row], v1 = lv1[row];
    int pid = lpid[row], prw = lprw[row];
    float cy, cx, half, sz, imgid, mylin;
    if (level == 0) {
        int b = pid >> 16, y = (pid >> 8) & 255, x = pid & 255;
        cy = (float)y + 0.5f; cx = (float)x + 0.5f;
        half = 0.5f; sz = 1.0f; imgid = (float)b; mylin = (float)pid;
    } else {
        int b = pid >> 12, R = (pid >> 6) & 63, X = pid & 63;
        cy = ((float)R + 0.5f) * 4.0f; cx = ((float)X + 0.5f) * 4.0f;
        half = 2.0f; sz = 4.0f; imgid = (float)b; mylin = (float)(OFFSET1 + pid);
    }
    float len = sqrtf(v0 * v0 + v1 * v1);
    float n0 = v0 / len, n1 = v1 / len;
    float rt0 = n1 * half, rt1 = -n0 * half;
    switch (kind) {
        case 0: return c ? (cx + rt1) : (cy + rt0);   // locs_lf
        case 1: return c ? (cx - rt1) : (cy - rt0);   // locs_rt
        case 2: return c ? n1 : n0;                   // norms
        case 3: return sz;                            // sizes
        case 4: return c ? cx : cy;                   // centers
        case 5: return imgid;                         // imgid
        case 6: return (float)prw;                    // p_rowids
        default: return mylin;                        // my_lin
    }
}

__device__ __forceinline__ void write_sections(float* __restrict__ out, int N,
                                               int rowStart, int cnt, int level,
                                               const float* lv0, const float* lv1,
                                               const int* lpid, const int* lprw,
                                               int tid) {
    const int mult[8] = {0, 2, 4, 6, 7, 9, 10, 11};
    const int wid[8]  = {2, 2, 2, 1, 2, 1, 1, 1};
    #pragma unroll 1
    for (int s = 0; s < 8; ++s) {
        int width = wid[s];
        float* P = out + (size_t)mult[s] * N + (size_t)width * rowStart;
        int total = width * cnt;
        int head = (int)((16 - ((uintptr_t)P & 15)) & 15) >> 2;
        if (head > total) head = total;
        if (tid < head)
            P[tid] = stage_val(s, width, tid, lv0, lv1, lpid, lprw, level);
        int nb4 = (total - head) >> 2;
        #pragma unroll 1
        for (int k = tid; k < nb4; k += 256) {
            int f = head + 4 * k;
            float4 v;
            v.x = stage_val(s, width, f + 0, lv0, lv1, lpid, lprw, level);
            v.y = stage_val(s, width, f + 1, lv0, lv1, lpid, lprw, level);
            v.z = stage_val(s, width, f + 2, lv0, lv1, lpid, lprw, level);
            v.w = stage_val(s, width, f + 3, lv0, lv1, lpid, lprw, level);
            *(float4*)(P + f) = v;
        }
        int done = head + 4 * nb4;
        int rem = total - done;
        if (tid < rem)
            P[done + tid] = stage_val(s, width, done + tid, lv0, lv1, lpid, lprw, level);
    }
}

// ---------------------------------------------------------------------------
// prepSa: S pass. Wave = (group, y-half): 2 output rows, 16 float4 loads/lane.
// Stages active rows in LDS; block writes its contiguous row span densely.
// ---------------------------------------------------------------------------
__global__ __launch_bounds__(256) void prepSa_kernel(const float* __restrict__ S,
                                                     const unsigned short* __restrict__ pred16,
                                                     const u64* __restrict__ mask1,
                                                     const int* __restrict__ offs0,
                                                     const int* __restrict__ offs1,
                                                     const int* __restrict__ totals,
                                                     float2* __restrict__ part,
                                                     float* __restrict__ out, int N) {
    __shared__ float lv0[1024], lv1[1024];
    __shared__ int lpid[1024], lprw[1024];

    int tid = threadIdx.x;
    int lane = tid & 63;
    int gh = blockIdx.x * 4 + (tid >> 6);            // 0..8191
    int g = gh >> 1, h = gh & 1;
    int bimg = g >> 6, R = g & 63;
    int g0 = blockIdx.x * 2;
    int rowStart = offs0[g0];

    unsigned pred = pred16[g * 64 + lane];
    u64 m1 = mask1[g];
    int base0 = offs0[g];
    int prow = totals[0] + offs1[g] + __popcll(m1 & ((1ull << lane) - 1ull));

    float wx[4], cwx[4];
    #pragma unroll
    for (int j = 0; j < 4; ++j) {
        int xi = 4 * lane + j;
        wx[j] = (float)(xi * 511) / 255.0f - (float)(8 * lane + 2 * j);
        cwx[j] = 1.0f - wx[j];
    }

    // input rows 8R+4h .. +3, cols 8*lane .. +7, both channels
    const float* Sa = S + (size_t)(2 * bimg) * 262144 + (8 * R + 4 * h) * 512 + 8 * lane;
    const float* Sq = Sa + 262144;
    float4 A[4], Ax[4], Q[4], Qx[4];
    #pragma unroll
    for (int k = 0; k < 4; ++k) {
        A[k]  = *(const float4*)(Sa + k * 512);
        Ax[k] = *(const float4*)(Sa + k * 512 + 4);
        Q[k]  = *(const float4*)(Sq + k * 512);
        Qx[k] = *(const float4*)(Sq + k * 512 + 4);
    }

    // actives in earlier half's rows (h==1 -> rows 0,1) — wave-uniform h
    int rc = 0;
    if (h) {
        #pragma unroll
        for (int r = 0; r < 2; ++r) {
            unsigned pr = (pred >> (4 * r)) & 0xF;
            rc += __popcll(__ballot((pr & 1) != 0)) + __popcll(__ballot((pr & 2) != 0)) +
                  __popcll(__ballot((pr & 4) != 0)) + __popcll(__ballot((pr & 8) != 0));
        }
    }

    float acc0 = 0.0f, acc1 = 0.0f;
    #pragma unroll
    for (int rr = 0; rr < 2; ++rr) {
        int r = 2 * h + rr;
        int y = 4 * R + r;
        float wy = (float)(y * 511) / 255.0f - (float)(2 * y);
        float cwy = 1.0f - wy;
        float4 lo = A[2*rr], loh = Ax[2*rr], hi = A[2*rr+1], hih = Ax[2*rr+1];
        float4 ql = Q[2*rr], qlh = Qx[2*rr], qh = Q[2*rr+1], qhh = Qx[2*rr+1];
        float va[4], vb[4];
        va[0] = (lo.x*cwy + hi.x*wy)*cwx[0] + (lo.y*cwy + hi.y*wy)*wx[0];
        va[1] = (lo.z*cwy + hi.z*wy)*cwx[1] + (lo.w*cwy + hi.w*wy)*wx[1];
        va[2] = (loh.x*cwy + hih.x*wy)*cwx[2] + (loh.y*cwy + hih.y*wy)*wx[2];
        va[3] = (loh.z*cwy + hih.z*wy)*cwx[3] + (loh.w*cwy + hih.w*wy)*wx[3];
        vb[0] = (ql.x*cwy + qh.x*wy)*cwx[0] + (ql.y*cwy + qh.y*wy)*wx[0];
        vb[1] = (ql.z*cwy + qh.z*wy)*cwx[1] + (ql.w*cwy + qh.w*wy)*wx[1];
        vb[2] = (qlh.x*cwy + qhh.x*wy)*cwx[2] + (qlh.y*cwy + qhh.y*wy)*wx[2];
        vb[3] = (qlh.z*cwy + qhh.z*wy)*cwx[3] + (qlh.w*cwy + qhh.w*wy)*wx[3];
        acc0 += va[0] + va[1] + va[2] + va[3];
        acc1 += vb[0] + vb[1] + vb[2] + vb[3];

        unsigned pr = (pred >> (4 * r)) & 0xF;
        u64 b0 = __ballot((pr & 1) != 0);
        u64 b1 = __ballot((pr & 2) != 0);
        u64 b2 = __ballot((pr & 4) != 0);
        u64 b3 = __ballot((pr & 8) != 0);
        u64 ltm = (1ull << lane) - 1ull;
        int pre = __popcll(b0 & ltm) + __popcll(b1 & ltm) +
                  __popcll(b2 & ltm) + __popcll(b3 & ltm);
        int rbase = base0 + rc + pre;
        int own = 0;
        #pragma unroll
        for (int j = 0; j < 4; ++j) {
            if (pr & (1u << j)) {
                int row = rbase + own;
                own++;
                int lr = row - rowStart;                 // < 1024 by construction
                lv0[lr] = va[j];
                lv1[lr] = vb[j];
                lpid[lr] = (bimg << 16) | (y << 8) | (4 * lane + j);
                lprw[lr] = prow;
            }
        }
        rc += __popcll(b0) + __popcll(b1) + __popcll(b2) + __popcll(b3);
    }

    part[gh * 64 + lane] = make_float2(acc0, acc1);

    __syncthreads();
    int cnt = offs0[g0 + 2] - rowStart;
    write_sections(out, N, rowStart, cnt, 0, lv0, lv1, lpid, lprw, tid);
}

// ---------------------------------------------------------------------------
// finish1: combine half partials per level-1 cell; staged dense writeout.
// Block = 4 groups -> contiguous L1 row span (<=256 rows).
// ---------------------------------------------------------------------------
__global__ __launch_bounds__(256) void finish1_kernel(const float2* __restrict__ part,
                                                      const u64* __restrict__ mask1,
                                                      const int* __restrict__ offs1,
                                                      const int* __restrict__ totals,
                                                      float* __restrict__ out, int N) {
    __shared__ float lv0[256], lv1[256];
    __shared__ int lpid[256], lprw[256];
    int tid = threadIdx.x, lane = tid & 63;
    int g = blockIdx.x * 4 + (tid >> 6);             // 0..4095
    int g0 = blockIdx.x * 4;
    int base1 = offs1[g0];
    int N0 = totals[0];

    u64 m1 = mask1[g];
    float2 p0 = part[(2 * g) * 64 + lane];
    float2 p1 = part[(2 * g + 1) * 64 + lane];
    if ((m1 >> lane) & 1ull) {
        int lr = (offs1[g] - base1) + __popcll(m1 & ((1ull << lane) - 1ull));
        lv0[lr] = (p0.x + p1.x) * (1.0f / 16.0f);
        lv1[lr] = (p0.y + p1.y) * (1.0f / 16.0f);
        lpid[lr] = g * 64 + lane;                    // b*4096 + R*64 + X
        lprw[lr] = N0 + base1 + lr;                  // own global row
    }
    __syncthreads();
    int cnt = offs1[g0 + 4] - base1;
    write_sections(out, N, N0 + base1, cnt, 1, lv0, lv1, lpid, lprw, tid);
}

extern "C" void kernel_launch(void* const* d_in, const int* in_sizes, int n_in,
                              void* d_out, int out_size, void* d_ws, size_t ws_size,
                              hipStream_t stream) {
    const float* E = (const float*)d_in[0];   // b_edges (64,1,512,512)
    const float* S = (const float*)d_in[1];   // sobel   (64,2,512,512)
    float* out = (float*)d_out;
    int N = out_size / 12;                    // 8 outputs = 12 floats/row

    // workspace layout (byte offsets); ~4.8 MB, all written before read
    char* ws = (char*)d_ws;
    int* counts0 = (int*)(ws + 0);            // 4096 ints
    int* counts1 = (int*)(ws + 16384);        // 4096
    int* offs0   = (int*)(ws + 32768);        // 4097 (sentinel at [4096])
    int* offs1   = (int*)(ws + 49216);        // 4097
    int* totals  = (int*)(ws + 65664);        // 2
    u64* mask1   = (u64*)(ws + 65728);        // 4096 u64 = 32 KB
    unsigned short* pred16 = (unsigned short*)(ws + 98496);  // 512 KB
    float2* part = (float2*)(ws + 622784);    // 8192*64 float2 = 4 MB

    prepE_kernel<<<1024, 256, 0, stream>>>(E, pred16, mask1, counts0, counts1);
    scan_kernel<<<1, 1024, 0, stream>>>(counts0, offs0, counts1, offs1, totals);
    prepSa_kernel<<<2048, 256, 0, stream>>>(S, pred16, mask1, offs0, offs1,
                                            totals, part, out, N);
    finish1_kernel<<<1024, 256, 0, stream>>>(part, mask1, offs1, totals, out, N);
}

// Round 9
// 82.066 us; speedup vs baseline: 1.0811x; 1.0811x over previous
//
#include <hip/hip_runtime.h>
#include <math.h>

// Fixed shapes: b_edges (64,1,512,512) f32, sobel (64,2,512,512) f32
// BASE=256, PY_SIZES=[256,64]
// Group g = b*64 + R owns output rows 4R..4R+3 (input rows 8R..8R+7).
// prepE: one wave per group; lane X owns cols 4X..4X+3 == one level-1 cell.
// sval : one wave per group; reads S only; writes compact 16B/row payload
//        {v0,v1,pid,prow} at the row's final global rank (+ L1 cell rows).
// expand: block = 256 consecutive rows; computes the 12 derived floats once
//        per row into LDS, then writes the 8 output sections densely.
// 512->256 align-corners: pos(i)=i*511/255 (exact f32 product, IEEE div),
// lo(i)=2i, w=pos-2i (i=255 -> w=1.0, bit-identical to the lo=hi=511 form).

typedef unsigned long long u64;
#define OFFSET1 4194304   // lin_id offset of level 1 (=64*256*256)

// ---------------------------------------------------------------------------
// prepE: E-only pass. 16 upfront float4 loads per lane, predicates for the
// lane's 16 pixels, ballots -> counts + masks.
// ---------------------------------------------------------------------------
__global__ __launch_bounds__(256) void prepE_kernel(const float* __restrict__ E,
                                                    unsigned short* __restrict__ pred16,
                                                    u64* __restrict__ mask1,
                                                    int* __restrict__ counts0,
                                                    int* __restrict__ counts1) {
    int lane = threadIdx.x & 63;
    int g = blockIdx.x * 4 + (threadIdx.x >> 6);     // 0..4095
    int b = g >> 6, R = g & 63;

    const float* Ep = E + b * 262144 + (8 * R) * 512 + 8 * lane;
    float4 L[8], H[8];
    #pragma unroll
    for (int k = 0; k < 8; ++k) {
        L[k] = *(const float4*)(Ep + k * 512);
        H[k] = *(const float4*)(Ep + k * 512 + 4);
    }

    float wx[4], cwx[4];
    #pragma unroll
    for (int j = 0; j < 4; ++j) {
        int xi = 4 * lane + j;
        wx[j] = (float)(xi * 511) / 255.0f - (float)(8 * lane + 2 * j);
        cwx[j] = 1.0f - wx[j];
    }

    unsigned pred = 0;
    int rc = 0;
    #pragma unroll
    for (int r = 0; r < 4; ++r) {
        int y = 4 * R + r;
        float wy = (float)(y * 511) / 255.0f - (float)(2 * y);
        float cwy = 1.0f - wy;
        float4 lo = L[2 * r], loh = H[2 * r];
        float4 hi = L[2 * r + 1], hih = H[2 * r + 1];
        float e0 = (lo.x*cwy + hi.x*wy)*cwx[0] + (lo.y*cwy + hi.y*wy)*wx[0];
        float e1 = (lo.z*cwy + hi.z*wy)*cwx[1] + (lo.w*cwy + hi.w*wy)*wx[1];
        float e2 = (loh.x*cwy + hih.x*wy)*cwx[2] + (loh.y*cwy + hih.y*wy)*wx[2];
        float e3 = (loh.z*cwy + hih.z*wy)*cwx[3] + (loh.w*cwy + hih.w*wy)*wx[3];
        bool p0 = (e0 != 0.0f), p1 = (e1 != 0.0f), p2 = (e2 != 0.0f), p3 = (e3 != 0.0f);
        pred |= (p0?1u:0u) << (4*r+0);
        pred |= (p1?1u:0u) << (4*r+1);
        pred |= (p2?1u:0u) << (4*r+2);
        pred |= (p3?1u:0u) << (4*r+3);
        u64 b0 = __ballot(p0), b1 = __ballot(p1), b2 = __ballot(p2), b3 = __ballot(p3);
        rc += __popcll(b0) + __popcll(b1) + __popcll(b2) + __popcll(b3);
    }
    u64 m1 = __ballot(pred != 0);
    pred16[g * 64 + lane] = (unsigned short)pred;
    if (lane == 0) {
        counts0[g] = rc;
        counts1[g] = __popcll(m1);
        mask1[g] = m1;
    }
}

// single-block exclusive scan of counts0[4096] and counts1[4096]
__global__ __launch_bounds__(1024) void scan_kernel(const int* __restrict__ counts0,
                                                    int* __restrict__ offs0,
                                                    const int* __restrict__ counts1,
                                                    int* __restrict__ offs1,
                                                    int* __restrict__ totals) {
    __shared__ int wsum[16];
    int tid = threadIdx.x, lane = tid & 63, wave = tid >> 6;

    int carry = 0;
    for (int base = 0; base < 4096; base += 1024) {
        int v = counts0[base + tid];
        int inc = v;
        #pragma unroll
        for (int d = 1; d < 64; d <<= 1) {
            int t = __shfl_up(inc, (unsigned)d, 64);
            if (lane >= d) inc += t;
        }
        if (lane == 63) wsum[wave] = inc;
        __syncthreads();
        int wbase = 0;
        for (int i = 0; i < wave; ++i) wbase += wsum[i];
        int tot = 0;
        #pragma unroll
        for (int i = 0; i < 16; ++i) tot += wsum[i];
        offs0[base + tid] = carry + wbase + inc - v;
        carry += tot;
        __syncthreads();
    }
    if (tid == 0) totals[0] = carry;

    int carry1 = 0;
    for (int base = 0; base < 4096; base += 1024) {
        int v = counts1[base + tid];
        int inc = v;
        #pragma unroll
        for (int d = 1; d < 64; d <<= 1) {
            int t = __shfl_up(inc, (unsigned)d, 64);
            if (lane >= d) inc += t;
        }
        if (lane == 63) wsum[wave] = inc;
        __syncthreads();
        int wbase = 0;
        for (int i = 0; i < wave; ++i) wbase += wsum[i];
        int tot = 0;
        #pragma unroll
        for (int i = 0; i < 16; ++i) tot += wsum[i];
        offs1[base + tid] = carry1 + wbase + inc - v;
        carry1 += tot;
        __syncthreads();
    }
    if (tid == 0) totals[1] = carry1;
}

// ---------------------------------------------------------------------------
// sval: S-only pass -> compact payload. Wave per group; two 16-load halves.
// payload[row] = {bits(v0), bits(v1), pid, prow}; L0 pid=(b<<16)|(y<<8)|x,
// L1 pid = OFFSET1 + b*4096 + R*64 + X (>= OFFSET1 tags the level).
// ---------------------------------------------------------------------------
__global__ __launch_bounds__(256) void sval_kernel(const float* __restrict__ S,
                                                   const unsigned short* __restrict__ pred16,
                                                   const u64* __restrict__ mask1,
                                                   const int* __restrict__ offs0,
                                                   const int* __restrict__ offs1,
                                                   const int* __restrict__ totals,
                                                   int4* __restrict__ payload) {
    int lane = threadIdx.x & 63;
    int g = blockIdx.x * 4 + (threadIdx.x >> 6);     // 0..4095
    int bimg = g >> 6, R = g & 63;

    unsigned pred = pred16[g * 64 + lane];
    u64 m1 = mask1[g];
    int base0 = offs0[g];
    int prow = totals[0] + offs1[g] + __popcll(m1 & ((1ull << lane) - 1ull));

    float wx[4], cwx[4];
    #pragma unroll
    for (int j = 0; j < 4; ++j) {
        int xi = 4 * lane + j;
        wx[j] = (float)(xi * 511) / 255.0f - (float)(8 * lane + 2 * j);
        cwx[j] = 1.0f - wx[j];
    }

    const float* Sa0 = S + (size_t)(2 * bimg) * 262144 + (8 * R) * 512 + 8 * lane;
    float acc0 = 0.0f, acc1 = 0.0f;
    int rc = 0;
    #pragma unroll
    for (int h = 0; h < 2; ++h) {
        const float* Sa = Sa0 + (4 * h) * 512;
        const float* Sq = Sa + 262144;
        float4 A[4], Ax[4], Q[4], Qx[4];
        #pragma unroll
        for (int k = 0; k < 4; ++k) {
            A[k]  = *(const float4*)(Sa + k * 512);
            Ax[k] = *(const float4*)(Sa + k * 512 + 4);
            Q[k]  = *(const float4*)(Sq + k * 512);
            Qx[k] = *(const float4*)(Sq + k * 512 + 4);
        }
        #pragma unroll
        for (int rr = 0; rr < 2; ++rr) {
            int r = 2 * h + rr;
            int y = 4 * R + r;
            float wy = (float)(y * 511) / 255.0f - (float)(2 * y);
            float cwy = 1.0f - wy;
            float4 lo = A[2*rr], loh = Ax[2*rr], hi = A[2*rr+1], hih = Ax[2*rr+1];
            float4 ql = Q[2*rr], qlh = Qx[2*rr], qh = Q[2*rr+1], qhh = Qx[2*rr+1];
            float va[4], vb[4];
            va[0] = (lo.x*cwy + hi.x*wy)*cwx[0] + (lo.y*cwy + hi.y*wy)*wx[0];
            va[1] = (lo.z*cwy + hi.z*wy)*cwx[1] + (lo.w*cwy + hi.w*wy)*wx[1];
            va[2] = (loh.x*cwy + hih.x*wy)*cwx[2] + (loh.y*cwy + hih.y*wy)*wx[2];
            va[3] = (loh.z*cwy + hih.z*wy)*cwx[3] + (loh.w*cwy + hih.w*wy)*wx[3];
            vb[0] = (ql.x*cwy + qh.x*wy)*cwx[0] + (ql.y*cwy + qh.y*wy)*wx[0];
            vb[1] = (ql.z*cwy + qh.z*wy)*cwx[1] + (ql.w*cwy + qh.w*wy)*wx[1];
            vb[2] = (qlh.x*cwy + qhh.x*wy)*cwx[2] + (qlh.y*cwy + qhh.y*wy)*wx[2];
            vb[3] = (qlh.z*cwy + qhh.z*wy)*cwx[3] + (qlh.w*cwy + qhh.w*wy)*wx[3];
            acc0 += va[0] + va[1] + va[2] + va[3];
            acc1 += vb[0] + vb[1] + vb[2] + vb[3];

            unsigned pr = (pred >> (4 * r)) & 0xF;
            u64 b0 = __ballot((pr & 1) != 0);
            u64 b1 = __ballot((pr & 2) != 0);
            u64 b2 = __ballot((pr & 4) != 0);
            u64 b3 = __ballot((pr & 8) != 0);
            u64 ltm = (1ull << lane) - 1ull;
            int pre = __popcll(b0 & ltm) + __popcll(b1 & ltm) +
                      __popcll(b2 & ltm) + __popcll(b3 & ltm);
            int rbase = base0 + rc + pre;
            int own = 0;
            #pragma unroll
            for (int j = 0; j < 4; ++j) {
                if (pr & (1u << j)) {
                    payload[rbase + own] =
                        make_int4(__float_as_int(va[j]), __float_as_int(vb[j]),
                                  (bimg << 16) | (y << 8) | (4 * lane + j), prow);
                    own++;
                }
            }
            rc += __popcll(b0) + __popcll(b1) + __popcll(b2) + __popcll(b3);
        }
    }

    if (pred != 0) {
        payload[prow] = make_int4(__float_as_int(acc0 * (1.0f / 16.0f)),
                                  __float_as_int(acc1 * (1.0f / 16.0f)),
                                  OFFSET1 + g * 64 + lane, prow);
    }
}

// ---------------------------------------------------------------------------
// expand: payload -> 8 dense output sections. 12 derived floats computed once
// per row into LDS (transposed [12][256], conflict-free), then dense writes.
// ---------------------------------------------------------------------------
__global__ __launch_bounds__(256) void expand_kernel(const int4* __restrict__ payload,
                                                     float* __restrict__ out, int N) {
    __shared__ float rowv[12][256];
    int t = threadIdx.x;
    int base = blockIdx.x * 256;
    int cnt = N - base; if (cnt > 256) cnt = 256;

    if (t < cnt) {
        int4 p = payload[base + t];
        float v0 = __int_as_float(p.x), v1 = __int_as_float(p.y);
        int pid = p.z, prw = p.w;
        float cy, cx, half, sz, mylin;
        int b;
        if (pid >= OFFSET1) {
            int lin = pid - OFFSET1;
            b = lin >> 12;
            int R = (lin >> 6) & 63, X = lin & 63;
            cy = ((float)R + 0.5f) * 4.0f; cx = ((float)X + 0.5f) * 4.0f;
            half = 2.0f; sz = 4.0f; mylin = (float)pid;
        } else {
            b = pid >> 16;
            int y = (pid >> 8) & 255, x = pid & 255;
            cy = (float)y + 0.5f; cx = (float)x + 0.5f;
            half = 0.5f; sz = 1.0f; mylin = (float)pid;
        }
        float len = sqrtf(v0 * v0 + v1 * v1);
        float n0 = v0 / len, n1 = v1 / len;
        float rt0 = n1 * half, rt1 = -n0 * half;
        rowv[0][t] = cy + rt0;  rowv[1][t] = cx + rt1;    // locs_lf
        rowv[2][t] = cy - rt0;  rowv[3][t] = cx - rt1;    // locs_rt
        rowv[4][t] = n0;        rowv[5][t] = n1;          // norms
        rowv[6][t] = sz;                                  // sizes
        rowv[7][t] = cy;        rowv[8][t] = cx;          // centers
        rowv[9][t] = (float)b;                            // imgid
        rowv[10][t] = (float)prw;                         // p_rowids
        rowv[11][t] = mylin;                              // my_lin
    }
    __syncthreads();

    const int mult[8] = {0, 2, 4, 6, 7, 9, 10, 11};
    const int wid[8]  = {2, 2, 2, 1, 2, 1, 1, 1};
    const int col[8]  = {0, 2, 4, 6, 7, 9, 10, 11};
    #pragma unroll 1
    for (int s = 0; s < 8; ++s) {
        int w = wid[s];
        float* P = out + (size_t)mult[s] * N + (size_t)w * base;
        int total = w * cnt;
        int head = (int)((16 - ((uintptr_t)P & 15)) & 15) >> 2;
        if (head > total) head = total;
        if (t < head) {
            int r = (w == 2) ? (t >> 1) : t;
            int c = (w == 2) ? (t & 1) : 0;
            P[t] = rowv[col[s] + c][r];
        }
        int nb4 = (total - head) >> 2;
        #pragma unroll 1
        for (int k = t; k < nb4; k += 256) {
            int f = head + 4 * k;
            float4 v;
            #pragma unroll
            for (int u = 0; u < 4; ++u) {
                int ff = f + u;
                int r = (w == 2) ? (ff >> 1) : ff;
                int c = (w == 2) ? (ff & 1) : 0;
                (&v.x)[u] = rowv[col[s] + c][r];
            }
            *(float4*)(P + f) = v;
        }
        int done = head + 4 * nb4;
        int rem = total - done;
        if (t < rem) {
            int ff = done + t;
            int r = (w == 2) ? (ff >> 1) : ff;
            int c = (w == 2) ? (ff & 1) : 0;
            P[ff] = rowv[col[s] + c][r];
        }
    }
}

extern "C" void kernel_launch(void* const* d_in, const int* in_sizes, int n_in,
                              void* d_out, int out_size, void* d_ws, size_t ws_size,
                              hipStream_t stream) {
    const float* E = (const float*)d_in[0];   // b_edges (64,1,512,512)
    const float* S = (const float*)d_in[1];   // sobel   (64,2,512,512)
    float* out = (float*)d_out;
    int N = out_size / 12;                    // 8 outputs = 12 floats/row

    // workspace layout (byte offsets); payload = 16B * N (~22 MB)
    char* ws = (char*)d_ws;
    int* counts0 = (int*)(ws + 0);            // 4096 ints
    int* counts1 = (int*)(ws + 16384);        // 4096
    int* offs0   = (int*)(ws + 32768);        // 4096
    int* offs1   = (int*)(ws + 49152);        // 4096
    int* totals  = (int*)(ws + 65536);        // 2
    u64* mask1   = (u64*)(ws + 65600);        // 4096 u64 = 32 KB
    unsigned short* pred16 = (unsigned short*)(ws + 98368);  // 512 KB
    int4* payload = (int4*)(ws + 622656);     // N * 16 B

    prepE_kernel<<<1024, 256, 0, stream>>>(E, pred16, mask1, counts0, counts1);
    scan_kernel<<<1, 1024, 0, stream>>>(counts0, offs0, counts1, offs1, totals);
    sval_kernel<<<1024, 256, 0, stream>>>(S, pred16, mask1, offs0, offs1,
                                          totals, payload);
    expand_kernel<<<(N + 255) / 256, 256, 0, stream>>>(payload, out, N);
}